// Round 16
// baseline (112.603 us; speedup 1.0000x reference)
//
#include <hip/hip_runtime.h>
#include <math.h>

#define NN 262144
#define PP 64
#define QQ 64
#define TT 2048
#define JJ 512
#define BB 8
#define HH 64
#define NSLOT 7
#define PSTR 520

__device__ __forceinline__ float lane_bcast(float v, int l) {
  return __int_as_float(__builtin_amdgcn_readlane(__float_as_int(v), l));
}

// ------- kernel 1: ew = exp(K.Scols); blocks 0-8 also compute seg_start -----
__global__ __launch_bounds__(256) void k_wp(const float* __restrict__ Kmat,
                                            const int* __restrict__ idx,
                                            const float* __restrict__ S,
                                            const int* __restrict__ seg_ids,
                                            float* __restrict__ ew,
                                            int* __restrict__ seg_start) {
  int tid = threadIdx.x;
  int gtid = blockIdx.x * 256 + tid;
  if (gtid <= TT) {
    int lo = 0, hi = NN;
    while (lo < hi) {
      int mid = (lo + hi) >> 1;
      if (seg_ids[mid] < gtid) lo = mid + 1; else hi = mid;
    }
    seg_start[gtid] = lo;
  }
  __shared__ __align__(16) float s_lds[BB * PP];  // [b][p]
  for (int i = tid; i < BB * PP; i += 256) {
    int p = i >> 3, b = i & 7;
    s_lds[b * PP + p] = S[p * JJ + idx[b]];
  }
  __syncthreads();
  int n = blockIdx.x * 64 + (tid >> 2);
  int sub = tid & 3;
  const float4* Kp = reinterpret_cast<const float4*>(Kmat + (size_t)n * PP + sub * 16);
  float4 kq[4];
#pragma unroll
  for (int j = 0; j < 4; ++j) kq[j] = Kp[j];
  float acc[8];
#pragma unroll
  for (int b = 0; b < 8; ++b) acc[b] = 0.f;
#pragma unroll
  for (int j4 = 0; j4 < 4; ++j4) {
    float4 kk = kq[j4];
#pragma unroll
    for (int b = 0; b < 8; ++b) {
      const float4 sv = *reinterpret_cast<const float4*>(&s_lds[b * PP + sub * 16 + j4 * 4]);
      acc[b] += kk.x * sv.x + kk.y * sv.y + kk.z * sv.z + kk.w * sv.w;
    }
  }
#pragma unroll
  for (int b = 0; b < 8; ++b) {
    acc[b] += __shfl_xor(acc[b], 1);
    acc[b] += __shfl_xor(acc[b], 2);
  }
  float ox = (sub == 0) ? acc[0] : (sub == 1) ? acc[2] : (sub == 2) ? acc[4] : acc[6];
  float oy = (sub == 0) ? acc[1] : (sub == 1) ? acc[3] : (sub == 2) ? acc[5] : acc[7];
  reinterpret_cast<float2*>(ew + (size_t)n * 8)[sub] =
      make_float2(__expf(ox), __expf(oy));
}

// ------- kernel 2: FIXED-SHAPE scatter-by-block partials --------------------
// Block = 32 contiguous rows, 4 waves x 8 rows, 6 upfront loads per lane,
// zero loops. Window touches <=2 segments (min seg len ~90 >> 32). Partial
// for t_lo -> P3[t_lo][blk - seg_start[t_lo]/32]; boundary blocks run a 2nd
// predicate pass (same live registers) -> P3[t_hi][0]. Collision-free slots,
// no atomics, every slot in [0,nb) written => no zero-init needed.
__global__ __launch_bounds__(256) void k_segB(const float* __restrict__ ew,
                                              const float* __restrict__ V,
                                              const int* __restrict__ seg_ids,
                                              const int* __restrict__ seg_start,
                                              float* __restrict__ P3) {
  __shared__ int seg_lds[32];
  __shared__ int slot_lds;
  __shared__ __align__(16) float accred[4][8][64];
  __shared__ float reds[4][8];
  int tid = threadIdx.x;
  int n0 = blockIdx.x * 32;
  if (tid < 32) seg_lds[tid] = seg_ids[n0 + tid];
  __syncthreads();
  int t_lo = seg_lds[0], t_hi = seg_lds[31];
  if (tid == 0) slot_lds = (int)blockIdx.x - (seg_start[t_lo] >> 5);

  int lane = tid & 63, w = tid >> 6;
  int rsub = lane >> 4, qg = lane & 15;
  int rA = w * 8 + rsub;          // local rows: A in {0..3,8..11,...}, B = A+4
  int rB = rA + 4;
  int tA = seg_lds[rA], tB = seg_lds[rB];

  // ---- all 6 loads upfront, no dependencies ----
  const float4* ePA = reinterpret_cast<const float4*>(ew + (size_t)(n0 + rA) * 8);
  const float4* ePB = reinterpret_cast<const float4*>(ew + (size_t)(n0 + rB) * 8);
  float4 eloA = ePA[0], ehiA = ePA[1];
  float4 eloB = ePB[0], ehiB = ePB[1];
  float4 vvA = reinterpret_cast<const float4*>(V + (size_t)(n0 + rA) * QQ)[qg];
  float4 vvB = reinterpret_cast<const float4*>(V + (size_t)(n0 + rB) * QQ)[qg];

#define PASS(TSEL, SLOT)                                                                                   \
  {                                                                                                        \
    float wA = (tA == (TSEL)) ? 1.f : 0.f;                                                                 \
    float wB = (tB == (TSEL)) ? 1.f : 0.f;                                                                 \
    float4 la = make_float4(eloA.x * wA, eloA.y * wA, eloA.z * wA, eloA.w * wA);                           \
    float4 ha = make_float4(ehiA.x * wA, ehiA.y * wA, ehiA.z * wA, ehiA.w * wA);                           \
    float4 lb = make_float4(eloB.x * wB, eloB.y * wB, eloB.z * wB, eloB.w * wB);                           \
    float4 hb = make_float4(ehiB.x * wB, ehiB.y * wB, ehiB.z * wB, ehiB.w * wB);                           \
    float4 acc[8];                                                                                         \
    acc[0] = make_float4(la.x * vvA.x + lb.x * vvB.x, la.x * vvA.y + lb.x * vvB.y,                         \
                         la.x * vvA.z + lb.x * vvB.z, la.x * vvA.w + lb.x * vvB.w);                        \
    acc[1] = make_float4(la.y * vvA.x + lb.y * vvB.x, la.y * vvA.y + lb.y * vvB.y,                         \
                         la.y * vvA.z + lb.y * vvB.z, la.y * vvA.w + lb.y * vvB.w);                        \
    acc[2] = make_float4(la.z * vvA.x + lb.z * vvB.x, la.z * vvA.y + lb.z * vvB.y,                         \
                         la.z * vvA.z + lb.z * vvB.z, la.z * vvA.w + lb.z * vvB.w);                        \
    acc[3] = make_float4(la.w * vvA.x + lb.w * vvB.x, la.w * vvA.y + lb.w * vvB.y,                         \
                         la.w * vvA.z + lb.w * vvB.z, la.w * vvA.w + lb.w * vvB.w);                        \
    acc[4] = make_float4(ha.x * vvA.x + hb.x * vvB.x, ha.x * vvA.y + hb.x * vvB.y,                         \
                         ha.x * vvA.z + hb.x * vvB.z, ha.x * vvA.w + hb.x * vvB.w);                        \
    acc[5] = make_float4(ha.y * vvA.x + hb.y * vvB.x, ha.y * vvA.y + hb.y * vvB.y,                         \
                         ha.y * vvA.z + hb.y * vvB.z, ha.y * vvA.w + hb.y * vvB.w);                        \
    acc[6] = make_float4(ha.z * vvA.x + hb.z * vvB.x, ha.z * vvA.y + hb.z * vvB.y,                         \
                         ha.z * vvA.z + hb.z * vvB.z, ha.z * vvA.w + hb.z * vvB.w);                        \
    acc[7] = make_float4(ha.w * vvA.x + hb.w * vvB.x, ha.w * vvA.y + hb.w * vvB.y,                         \
                         ha.w * vvA.z + hb.w * vvB.z, ha.w * vvA.w + hb.w * vvB.w);                        \
    float se[8] = {la.x + lb.x, la.y + lb.y, la.z + lb.z, la.w + lb.w,                                     \
                   ha.x + hb.x, ha.y + hb.y, ha.z + hb.z, ha.w + hb.w};                                    \
    _Pragma("unroll")                                                                                      \
    for (int b = 0; b < 8; ++b) {                                                                          \
      acc[b].x += __shfl_xor(acc[b].x, 16); acc[b].y += __shfl_xor(acc[b].y, 16);                          \
      acc[b].z += __shfl_xor(acc[b].z, 16); acc[b].w += __shfl_xor(acc[b].w, 16);                          \
      acc[b].x += __shfl_xor(acc[b].x, 32); acc[b].y += __shfl_xor(acc[b].y, 32);                          \
      acc[b].z += __shfl_xor(acc[b].z, 32); acc[b].w += __shfl_xor(acc[b].w, 32);                          \
      se[b] += __shfl_xor(se[b], 16);                                                                      \
      se[b] += __shfl_xor(se[b], 32);                                                                      \
    }                                                                                                      \
    if (rsub == 0) {                                                                                       \
      _Pragma("unroll")                                                                                    \
      for (int b = 0; b < 8; ++b)                                                                          \
        *reinterpret_cast<float4*>(&accred[w][b][qg * 4]) = acc[b];                                        \
      if (qg == 0) {                                                                                       \
        _Pragma("unroll")                                                                                  \
        for (int b = 0; b < 8; ++b) reds[w][b] = se[b];                                                    \
      }                                                                                                    \
    }                                                                                                      \
    __syncthreads();                                                                                       \
    {                                                                                                      \
      float* Pp = P3 + ((size_t)(TSEL) * NSLOT + (SLOT)) * PSTR;                                           \
      for (int o = tid; o < 512; o += 256) {                                                               \
        int b = o >> 6, q = o & 63;                                                                        \
        Pp[o] = accred[0][b][q] + accred[1][b][q] + accred[2][b][q] + accred[3][b][q];                     \
      }                                                                                                    \
      if (tid < 8)                                                                                         \
        Pp[512 + tid] = reds[0][tid] + reds[1][tid] + reds[2][tid] + reds[3][tid];                         \
    }                                                                                                      \
  }

  __syncthreads();   // slot_lds ready; also orders LDS reuse
  int slot_lo = slot_lds;
  PASS(t_lo, slot_lo);
  if (t_lo != t_hi) {
    __syncthreads();
    PASS(t_hi, 0);
  }
#undef PASS
}

// ------- kernel 3: gather <=7 slots per segment, normalize -> M -------------
__global__ __launch_bounds__(256) void k_red(const float* __restrict__ P3,
                                             const int* __restrict__ seg_start,
                                             float* __restrict__ M) {
  __shared__ float invL[8];
  int t = blockIdx.x, tid = threadIdx.x;
  int s = seg_start[t], e = seg_start[t + 1];
  int b0 = s >> 5;
  int nb = (e > s) ? (((e - 1) >> 5) - b0 + 1) : 0;
  if (tid < 8) {
    float dd = 0.f;
#pragma unroll
    for (int jb = 0; jb < NSLOT; ++jb) {
      int jc = (jb < nb) ? jb : 0;
      float v = P3[((size_t)t * NSLOT + jc) * PSTR + 512 + tid];
      dd += (jb < nb) ? v : 0.f;
    }
    invL[tid] = (dd > 0.f) ? 1.f / dd : 0.f;
  }
  __syncthreads();
  for (int o = tid; o < 512; o += 256) {
    int b = o >> 6;
    float sum = 0.f;
#pragma unroll
    for (int jb = 0; jb < NSLOT; ++jb) {
      int jc = (jb < nb) ? jb : 0;
      float v = P3[((size_t)t * NSLOT + jc) * PSTR + o];
      sum += (jb < nb) ? v : 0.f;
    }
    M[(size_t)t * 512 + o] = sum * invL[b];
  }
}

// -------- kernel 4: GI[rho][g] = W_ih[g,:] . X[rho,:] + b_ih ----------------
__global__ __launch_bounds__(256) void k_gi(const float* __restrict__ M,
                                            const float* __restrict__ W_ih,
                                            const float* __restrict__ b_ih,
                                            float* __restrict__ GI) {
  __shared__ float Wt[64 * 193];
  int tid = threadIdx.x;
  for (int i = tid; i < 192 * 64; i += 256) {
    int g = i >> 6, k = i & 63;
    Wt[k * 193 + g] = W_ih[i];
  }
  __syncthreads();
  int lane = tid & 63, wv = tid >> 6;
  int row0 = blockIdx.x * 32 + wv * 8;
  float x[8];
#pragma unroll
  for (int rr = 0; rr < 8; ++rr) {
    int rho = row0 + rr;
    int b = rho >> 11, t = rho & 2047;
    x[rr] = M[((size_t)t * 8 + b) * 64 + lane];
  }
  float bi0 = b_ih[lane], bi1 = b_ih[64 + lane], bi2 = b_ih[128 + lane];
  float a0[8], a1[8], a2[8];
#pragma unroll
  for (int rr = 0; rr < 8; ++rr) { a0[rr] = bi0; a1[rr] = bi1; a2[rr] = bi2; }
#pragma unroll
  for (int k = 0; k < 64; ++k) {
    float w0 = Wt[k * 193 + lane];
    float w1 = Wt[k * 193 + 64 + lane];
    float w2 = Wt[k * 193 + 128 + lane];
#pragma unroll
    for (int rr = 0; rr < 8; ++rr) {
      float xk = lane_bcast(x[rr], k);
      a0[rr] += w0 * xk; a1[rr] += w1 * xk; a2[rr] += w2 * xk;
    }
  }
#pragma unroll
  for (int rr = 0; rr < 8; ++rr) {
    size_t rho = (size_t)row0 + rr;
    GI[rho * 192 + lane]       = a0[rr];
    GI[rho * 192 + 64 + lane]  = a1[rr];
    GI[rho * 192 + 128 + lane] = a2[rr];
  }
}

// -------- kernel 5: GRU, one t-row per wave, b128 W reads, padded LDS -------
__global__ __launch_bounds__(256) void k_gru(const float* __restrict__ GI,
                                             const float* __restrict__ W_hh,
                                             const float* __restrict__ b_hh,
                                             const float* __restrict__ w_out,
                                             const float* __restrict__ b_out,
                                             float* __restrict__ preds) {
  __shared__ __align__(16) float Wl[192 * 68];
  int tid = threadIdx.x;
  for (int i = tid; i < 192 * 16; i += 256) {
    int g = i >> 4, c = i & 15;
    *reinterpret_cast<float4*>(&Wl[g * 68 + c * 4]) =
        *reinterpret_cast<const float4*>(W_hh + g * 64 + c * 4);
  }
  __syncthreads();
  int lane = tid & 63, wv = tid >> 6;
  int t = blockIdx.x * 4 + wv;
  float bh0 = b_hh[lane], bh1 = b_hh[64 + lane], bh2 = b_hh[128 + lane];
  float wo = w_out[lane];
  float bo = b_out[0];
  const float* w0base = &Wl[lane * 68];
  const float* w1base = &Wl[(64 + lane) * 68];
  const float* w2base = &Wl[(128 + lane) * 68];

  float gr[8], gz[8], gn[8];
#pragma unroll
  for (int b = 0; b < 8; ++b) {
    size_t base = ((size_t)b * TT + t) * 192;
    gr[b] = GI[base + lane];
    gz[b] = GI[base + 64 + lane];
    gn[b] = GI[base + 128 + lane];
  }

  float h;
  {
    float r = 1.f / (1.f + __expf(-(gr[0] + bh0)));
    float z = 1.f / (1.f + __expf(-(gz[0] + bh1)));
    float nv = tanhf(gn[0] + r * bh2);
    h = (1.f - z) * nv;
    float pv = h * wo;
#pragma unroll
    for (int off = 32; off; off >>= 1) pv += __shfl_xor(pv, off);
    if (lane == 0) preds[t] = pv + bo;
  }
#pragma unroll
  for (int b = 1; b < 8; ++b) {
    float ar = bh0, az = bh1, an = bh2;
#pragma unroll
    for (int c = 0; c < 16; ++c) {
      const float4 w0 = *reinterpret_cast<const float4*>(w0base + c * 4);
      const float4 w1 = *reinterpret_cast<const float4*>(w1base + c * 4);
      const float4 w2 = *reinterpret_cast<const float4*>(w2base + c * 4);
      float a0 = lane_bcast(h, c * 4 + 0), a1 = lane_bcast(h, c * 4 + 1);
      float a2 = lane_bcast(h, c * 4 + 2), a3 = lane_bcast(h, c * 4 + 3);
      ar += w0.x * a0 + w0.y * a1 + w0.z * a2 + w0.w * a3;
      az += w1.x * a0 + w1.y * a1 + w1.z * a2 + w1.w * a3;
      an += w2.x * a0 + w2.y * a1 + w2.z * a2 + w2.w * a3;
    }
    float r = 1.f / (1.f + __expf(-(gr[b] + ar)));
    float z = 1.f / (1.f + __expf(-(gz[b] + az)));
    float nv = tanhf(gn[b] + r * an);
    h = (1.f - z) * nv + z * h;
    float pv = h * wo;
#pragma unroll
    for (int off = 32; off; off >>= 1) pv += __shfl_xor(pv, off);
    if (lane == 0) preds[(size_t)b * TT + t] = pv + bo;
  }
}

extern "C" void kernel_launch(void* const* d_in, const int* in_sizes, int n_in,
                              void* d_out, int out_size, void* d_ws, size_t ws_size,
                              hipStream_t stream) {
  const int*   idx     = (const int*)d_in[0];
  const int*   seg_ids = (const int*)d_in[1];
  const float* Kmat    = (const float*)d_in[2];
  const float* V       = (const float*)d_in[3];
  const float* S       = (const float*)d_in[4];
  const float* W_ih    = (const float*)d_in[5];
  const float* W_hh    = (const float*)d_in[6];
  const float* b_ih    = (const float*)d_in[7];
  const float* b_hh    = (const float*)d_in[8];
  const float* w_out   = (const float*)d_in[9];
  const float* b_out   = (const float*)d_in[10];
  float* out = (float*)d_out;

  char* ws = (char*)d_ws;
  int*   seg_start = (int*)(ws + 0);       // (T+1) ints         8448 B
  float* ew = (float*)(ws + 8448);         // N*8 f              8.4 MB
  float* M  = (float*)(ws + 8397056);      // T*8*64 f           4.2 MB
  float* P3 = (float*)(ws + 12591360);     // T*7*520 f         29.8 MB
  float* GI = (float*)(ws + 12591360);     // 8*T*192 f  (aliases P3; P3 dead by k_gi)

  hipLaunchKernelGGL(k_wp, dim3(NN / 64), dim3(256), 0, stream,
                     Kmat, idx, S, seg_ids, ew, seg_start);
  hipLaunchKernelGGL(k_segB, dim3(NN / 32), dim3(256), 0, stream,
                     ew, V, seg_ids, seg_start, P3);
  hipLaunchKernelGGL(k_red, dim3(TT), dim3(256), 0, stream, P3, seg_start, M);
  hipLaunchKernelGGL(k_gi, dim3(512), dim3(256), 0, stream, M, W_ih, b_ih, GI);
  hipLaunchKernelGGL(k_gru, dim3(512), dim3(256), 0, stream, GI, W_hh, b_hh, w_out, b_out, out);
}

// Round 17
// 88.262 us; speedup vs baseline: 1.2758x; 1.2758x over previous
//
#include <hip/hip_runtime.h>
#include <math.h>

#define NN 262144
#define PP 64
#define QQ 64
#define TT 2048
#define JJ 512
#define BB 8
#define HH 64
#define PSTR 520

__device__ __forceinline__ float lane_bcast(float v, int l) {
  return __int_as_float(__builtin_amdgcn_readlane(__float_as_int(v), l));
}

// ------- kernel 1: FUSED  ew(LDS) = exp(K.Scols) -> windowed V partials -----
// Block = 64 contiguous rows. V preloaded to registers BEFORE phase 1 (its
// HBM latency hides under the K math). ew never touches global memory.
// Partials are window-addressed: P3[blk][tt - t_lo], tt over the <=3
// segments this window spans. Blocks 0..8 also compute seg_start (used only
// by later kernels).
__global__ __launch_bounds__(256) void k_fused3(const float* __restrict__ Kmat,
                                                const int* __restrict__ idx,
                                                const float* __restrict__ S,
                                                const float* __restrict__ V,
                                                const int* __restrict__ seg_ids,
                                                float* __restrict__ P3,
                                                int* __restrict__ seg_start) {
  __shared__ __align__(16) float s_cols[BB * PP];   // [b][p]
  __shared__ __align__(16) float ew_lds[64 * 8];    // [r][b]
  __shared__ int seg_lds[64];
  __shared__ __align__(16) float accred[4][8][64];
  __shared__ float reds[4][8];
  int tid = threadIdx.x;
  int n0 = blockIdx.x * 64;
  int gtid = blockIdx.x * 256 + tid;
  if (gtid <= TT) {   // folded seg_start searches (blocks 0..8)
    int lo = 0, hi = NN;
    while (lo < hi) {
      int mid = (lo + hi) >> 1;
      if (seg_ids[mid] < gtid) lo = mid + 1; else hi = mid;
    }
    seg_start[gtid] = lo;
  }
  if (tid < 64) seg_lds[tid] = seg_ids[n0 + tid];
  for (int i = tid; i < BB * PP; i += 256) {
    int p = i >> 3, b = i & 7;
    s_cols[b * PP + p] = S[p * JJ + idx[b]];
  }

  int lane = tid & 63, w = tid >> 6;
  int rsub = lane >> 4, qg = lane & 15;

  // ---- V preload: 4 quads per wave, issued before any dependent work ----
  float4 vv[4];
#pragma unroll
  for (int qi = 0; qi < 4; ++qi) {
    int rl = w * 16 + qi * 4 + rsub;
    vv[qi] = reinterpret_cast<const float4*>(V + (size_t)(n0 + rl) * QQ)[qg];
  }
  __syncthreads();   // s_cols ready

  // ---- phase 1: k_w math, 64 rows, ew -> LDS ----
  {
    int row = tid >> 2;          // local row 0..63
    int sub = tid & 3;
    const float4* Kp = reinterpret_cast<const float4*>(Kmat + (size_t)(n0 + row) * PP + sub * 16);
    float4 kq[4];
#pragma unroll
    for (int j = 0; j < 4; ++j) kq[j] = Kp[j];
    float a8[8];
#pragma unroll
    for (int b = 0; b < 8; ++b) a8[b] = 0.f;
#pragma unroll
    for (int j4 = 0; j4 < 4; ++j4) {
      float4 kk = kq[j4];
#pragma unroll
      for (int b = 0; b < 8; ++b) {
        const float4 sv = *reinterpret_cast<const float4*>(&s_cols[b * PP + sub * 16 + j4 * 4]);
        a8[b] += kk.x * sv.x + kk.y * sv.y + kk.z * sv.z + kk.w * sv.w;
      }
    }
#pragma unroll
    for (int b = 0; b < 8; ++b) {
      a8[b] += __shfl_xor(a8[b], 1);
      a8[b] += __shfl_xor(a8[b], 2);
    }
    float ox = (sub == 0) ? a8[0] : (sub == 1) ? a8[2] : (sub == 2) ? a8[4] : a8[6];
    float oy = (sub == 0) ? a8[1] : (sub == 1) ? a8[3] : (sub == 2) ? a8[5] : a8[7];
    *reinterpret_cast<float2*>(&ew_lds[row * 8 + 2 * sub]) =
        make_float2(__expf(ox), __expf(oy));
  }
  __syncthreads();

  // ---- phase 2: predicated per-segment passes ----
  int t_lo = seg_lds[0], t_hi = seg_lds[63];
  int npass = t_hi - t_lo + 1; if (npass > 3) npass = 3;
  int tq[4];
#pragma unroll
  for (int qi = 0; qi < 4; ++qi) tq[qi] = seg_lds[w * 16 + qi * 4 + rsub];

  for (int pi = 0; pi < npass; ++pi) {
    int tt = t_lo + pi;
    float4 acc[8];
#pragma unroll
    for (int b = 0; b < 8; ++b) acc[b] = make_float4(0.f, 0.f, 0.f, 0.f);
    float se[8];
#pragma unroll
    for (int b = 0; b < 8; ++b) se[b] = 0.f;
#pragma unroll
    for (int qi = 0; qi < 4; ++qi) {
      int rl = w * 16 + qi * 4 + rsub;
      float wq = (tq[qi] == tt) ? 1.f : 0.f;
      float4 elo = *reinterpret_cast<const float4*>(&ew_lds[rl * 8]);
      float4 ehi = *reinterpret_cast<const float4*>(&ew_lds[rl * 8 + 4]);
      elo.x *= wq; elo.y *= wq; elo.z *= wq; elo.w *= wq;
      ehi.x *= wq; ehi.y *= wq; ehi.z *= wq; ehi.w *= wq;
      se[0] += elo.x; se[1] += elo.y; se[2] += elo.z; se[3] += elo.w;
      se[4] += ehi.x; se[5] += ehi.y; se[6] += ehi.z; se[7] += ehi.w;
      float4 v4 = vv[qi];
      acc[0].x += elo.x * v4.x; acc[0].y += elo.x * v4.y; acc[0].z += elo.x * v4.z; acc[0].w += elo.x * v4.w;
      acc[1].x += elo.y * v4.x; acc[1].y += elo.y * v4.y; acc[1].z += elo.y * v4.z; acc[1].w += elo.y * v4.w;
      acc[2].x += elo.z * v4.x; acc[2].y += elo.z * v4.y; acc[2].z += elo.z * v4.z; acc[2].w += elo.z * v4.w;
      acc[3].x += elo.w * v4.x; acc[3].y += elo.w * v4.y; acc[3].z += elo.w * v4.z; acc[3].w += elo.w * v4.w;
      acc[4].x += ehi.x * v4.x; acc[4].y += ehi.x * v4.y; acc[4].z += ehi.x * v4.z; acc[4].w += ehi.x * v4.w;
      acc[5].x += ehi.y * v4.x; acc[5].y += ehi.y * v4.y; acc[5].z += ehi.y * v4.z; acc[5].w += ehi.y * v4.w;
      acc[6].x += ehi.z * v4.x; acc[6].y += ehi.z * v4.y; acc[6].z += ehi.z * v4.z; acc[6].w += ehi.z * v4.w;
      acc[7].x += ehi.w * v4.x; acc[7].y += ehi.w * v4.y; acc[7].z += ehi.w * v4.z; acc[7].w += ehi.w * v4.w;
    }
#pragma unroll
    for (int b = 0; b < 8; ++b) {
      acc[b].x += __shfl_xor(acc[b].x, 16); acc[b].y += __shfl_xor(acc[b].y, 16);
      acc[b].z += __shfl_xor(acc[b].z, 16); acc[b].w += __shfl_xor(acc[b].w, 16);
      acc[b].x += __shfl_xor(acc[b].x, 32); acc[b].y += __shfl_xor(acc[b].y, 32);
      acc[b].z += __shfl_xor(acc[b].z, 32); acc[b].w += __shfl_xor(acc[b].w, 32);
      se[b] += __shfl_xor(se[b], 16);
      se[b] += __shfl_xor(se[b], 32);
    }
    if (rsub == 0) {
#pragma unroll
      for (int b = 0; b < 8; ++b)
        *reinterpret_cast<float4*>(&accred[w][b][qg * 4]) = acc[b];
      if (qg == 0) {
#pragma unroll
        for (int b = 0; b < 8; ++b) reds[w][b] = se[b];
      }
    }
    __syncthreads();
    float* Pp = P3 + ((size_t)blockIdx.x * 3 + pi) * PSTR;
    for (int o = tid; o < 512; o += 256) {
      int b = o >> 6, q = o & 63;
      Pp[o] = accred[0][b][q] + accred[1][b][q] + accred[2][b][q] + accred[3][b][q];
    }
    if (tid < 8)
      Pp[512 + tid] = reds[0][tid] + reds[1][tid] + reds[2][tid] + reds[3][tid];
    __syncthreads();   // protect accred before next pass
  }
}

// ------- kernel 2: gather <=4 windows per segment, normalize -> M -----------
__global__ __launch_bounds__(256) void k_red(const float* __restrict__ P3,
                                             const int* __restrict__ seg_start,
                                             const int* __restrict__ seg_ids,
                                             float* __restrict__ M) {
  __shared__ float invL[8];
  __shared__ int slotw[4];   // encoded (window*3+slot) or -1
  int t = blockIdx.x, tid = threadIdx.x;
  int s = seg_start[t], e = seg_start[t + 1];
  int w0 = s >> 6;
  int nb = (e > s) ? (((e - 1) >> 6) - w0 + 1) : 0;
  if (tid < 4) {
    int valid = (tid < nb);
    int wdx = valid ? (w0 + tid) : w0;
    int tag = seg_ids[wdx * 64];     // t_lo of that window
    int slot = t - tag;
    valid = valid && (slot >= 0) && (slot < 3);
    slotw[tid] = valid ? (wdx * 3 + slot) : -1;
  }
  __syncthreads();
  if (tid < 8) {
    float dd = 0.f;
#pragma unroll
    for (int wi = 0; wi < 4; ++wi) {
      int sw = slotw[wi];
      int swc = (sw >= 0) ? sw : 0;
      float v = P3[(size_t)swc * PSTR + 512 + tid];
      dd += (sw >= 0) ? v : 0.f;
    }
    invL[tid] = (dd > 0.f) ? 1.f / dd : 0.f;
  }
  __syncthreads();
  for (int o = tid; o < 512; o += 256) {
    int b = o >> 6;
    float sum = 0.f;
#pragma unroll
    for (int wi = 0; wi < 4; ++wi) {
      int sw = slotw[wi];
      int swc = (sw >= 0) ? sw : 0;
      float v = P3[(size_t)swc * PSTR + o];
      sum += (sw >= 0) ? v : 0.f;
    }
    M[(size_t)t * 512 + o] = sum * invL[b];
  }
}

// -------- kernel 3: GI[rho][g] = W_ih[g,:] . X[rho,:] + b_ih ----------------
__global__ __launch_bounds__(256) void k_gi(const float* __restrict__ M,
                                            const float* __restrict__ W_ih,
                                            const float* __restrict__ b_ih,
                                            float* __restrict__ GI) {
  __shared__ float Wt[64 * 193];
  int tid = threadIdx.x;
  for (int i = tid; i < 192 * 64; i += 256) {
    int g = i >> 6, k = i & 63;
    Wt[k * 193 + g] = W_ih[i];
  }
  __syncthreads();
  int lane = tid & 63, wv = tid >> 6;
  int row0 = blockIdx.x * 32 + wv * 8;
  float x[8];
#pragma unroll
  for (int rr = 0; rr < 8; ++rr) {
    int rho = row0 + rr;
    int b = rho >> 11, t = rho & 2047;
    x[rr] = M[((size_t)t * 8 + b) * 64 + lane];
  }
  float bi0 = b_ih[lane], bi1 = b_ih[64 + lane], bi2 = b_ih[128 + lane];
  float a0[8], a1[8], a2[8];
#pragma unroll
  for (int rr = 0; rr < 8; ++rr) { a0[rr] = bi0; a1[rr] = bi1; a2[rr] = bi2; }
#pragma unroll
  for (int k = 0; k < 64; ++k) {
    float w0 = Wt[k * 193 + lane];
    float w1 = Wt[k * 193 + 64 + lane];
    float w2 = Wt[k * 193 + 128 + lane];
#pragma unroll
    for (int rr = 0; rr < 8; ++rr) {
      float xk = lane_bcast(x[rr], k);
      a0[rr] += w0 * xk; a1[rr] += w1 * xk; a2[rr] += w2 * xk;
    }
  }
#pragma unroll
  for (int rr = 0; rr < 8; ++rr) {
    size_t rho = (size_t)row0 + rr;
    GI[rho * 192 + lane]       = a0[rr];
    GI[rho * 192 + 64 + lane]  = a1[rr];
    GI[rho * 192 + 128 + lane] = a2[rr];
  }
}

// -------- kernel 4: GRU, one t-row per wave, b128 W reads, padded LDS -------
__global__ __launch_bounds__(256) void k_gru(const float* __restrict__ GI,
                                             const float* __restrict__ W_hh,
                                             const float* __restrict__ b_hh,
                                             const float* __restrict__ w_out,
                                             const float* __restrict__ b_out,
                                             float* __restrict__ preds) {
  __shared__ __align__(16) float Wl[192 * 68];
  int tid = threadIdx.x;
  for (int i = tid; i < 192 * 16; i += 256) {
    int g = i >> 4, c = i & 15;
    *reinterpret_cast<float4*>(&Wl[g * 68 + c * 4]) =
        *reinterpret_cast<const float4*>(W_hh + g * 64 + c * 4);
  }
  __syncthreads();
  int lane = tid & 63, wv = tid >> 6;
  int t = blockIdx.x * 4 + wv;
  float bh0 = b_hh[lane], bh1 = b_hh[64 + lane], bh2 = b_hh[128 + lane];
  float wo = w_out[lane];
  float bo = b_out[0];
  const float* w0base = &Wl[lane * 68];
  const float* w1base = &Wl[(64 + lane) * 68];
  const float* w2base = &Wl[(128 + lane) * 68];

  float gr[8], gz[8], gn[8];
#pragma unroll
  for (int b = 0; b < 8; ++b) {
    size_t base = ((size_t)b * TT + t) * 192;
    gr[b] = GI[base + lane];
    gz[b] = GI[base + 64 + lane];
    gn[b] = GI[base + 128 + lane];
  }

  float h;
  {
    float r = 1.f / (1.f + __expf(-(gr[0] + bh0)));
    float z = 1.f / (1.f + __expf(-(gz[0] + bh1)));
    float nv = tanhf(gn[0] + r * bh2);
    h = (1.f - z) * nv;
    float pv = h * wo;
#pragma unroll
    for (int off = 32; off; off >>= 1) pv += __shfl_xor(pv, off);
    if (lane == 0) preds[t] = pv + bo;
  }
#pragma unroll
  for (int b = 1; b < 8; ++b) {
    float ar = bh0, az = bh1, an = bh2;
#pragma unroll
    for (int c = 0; c < 16; ++c) {
      const float4 w0 = *reinterpret_cast<const float4*>(w0base + c * 4);
      const float4 w1 = *reinterpret_cast<const float4*>(w1base + c * 4);
      const float4 w2 = *reinterpret_cast<const float4*>(w2base + c * 4);
      float a0 = lane_bcast(h, c * 4 + 0), a1 = lane_bcast(h, c * 4 + 1);
      float a2 = lane_bcast(h, c * 4 + 2), a3 = lane_bcast(h, c * 4 + 3);
      ar += w0.x * a0 + w0.y * a1 + w0.z * a2 + w0.w * a3;
      az += w1.x * a0 + w1.y * a1 + w1.z * a2 + w1.w * a3;
      an += w2.x * a0 + w2.y * a1 + w2.z * a2 + w2.w * a3;
    }
    float r = 1.f / (1.f + __expf(-(gr[b] + ar)));
    float z = 1.f / (1.f + __expf(-(gz[b] + az)));
    float nv = tanhf(gn[b] + r * an);
    h = (1.f - z) * nv + z * h;
    float pv = h * wo;
#pragma unroll
    for (int off = 32; off; off >>= 1) pv += __shfl_xor(pv, off);
    if (lane == 0) preds[(size_t)b * TT + t] = pv + bo;
  }
}

extern "C" void kernel_launch(void* const* d_in, const int* in_sizes, int n_in,
                              void* d_out, int out_size, void* d_ws, size_t ws_size,
                              hipStream_t stream) {
  const int*   idx     = (const int*)d_in[0];
  const int*   seg_ids = (const int*)d_in[1];
  const float* Kmat    = (const float*)d_in[2];
  const float* V       = (const float*)d_in[3];
  const float* S       = (const float*)d_in[4];
  const float* W_ih    = (const float*)d_in[5];
  const float* W_hh    = (const float*)d_in[6];
  const float* b_ih    = (const float*)d_in[7];
  const float* b_hh    = (const float*)d_in[8];
  const float* w_out   = (const float*)d_in[9];
  const float* b_out   = (const float*)d_in[10];
  float* out = (float*)d_out;

  char* ws = (char*)d_ws;
  int*   seg_start = (int*)(ws + 0);       // (T+1) ints          8448 B
  float* P3 = (float*)(ws + 8448);         // 4096*3*520 f       25.6 MB
  float* M  = (float*)(ws + 25567488);     // T*8*64 f            4.2 MB
  float* GI = (float*)(ws + 29761792);     // 8*T*192 f          12.6 MB (end 42.3 MB)

  hipLaunchKernelGGL(k_fused3, dim3(NN / 64), dim3(256), 0, stream,
                     Kmat, idx, S, V, seg_ids, P3, seg_start);
  hipLaunchKernelGGL(k_red, dim3(TT), dim3(256), 0, stream, P3, seg_start, seg_ids, M);
  hipLaunchKernelGGL(k_gi, dim3(512), dim3(256), 0, stream, M, W_ih, b_ih, GI);
  hipLaunchKernelGGL(k_gru, dim3(512), dim3(256), 0, stream, GI, W_hh, b_hh, w_out, b_out, out);
}

// Round 18
// 70.131 us; speedup vs baseline: 1.6056x; 1.2585x over previous
//
#include <hip/hip_runtime.h>
#include <math.h>

#define NN 262144
#define PP 64
#define QQ 64
#define TT 2048
#define JJ 512
#define BB 8
#define HH 64

__device__ __forceinline__ float lane_bcast(float v, int l) {
  return __int_as_float(__builtin_amdgcn_readlane(__float_as_int(v), l));
}

// ------- kernel 1: ew = exp(K.Scols); blocks 0-8 also compute seg_start -----
__global__ __launch_bounds__(256) void k_wp(const float* __restrict__ Kmat,
                                            const int* __restrict__ idx,
                                            const float* __restrict__ S,
                                            const int* __restrict__ seg_ids,
                                            float* __restrict__ ew,
                                            int* __restrict__ seg_start) {
  int tid = threadIdx.x;
  int gtid = blockIdx.x * 256 + tid;
  if (gtid <= TT) {
    int lo = 0, hi = NN;
    while (lo < hi) {
      int mid = (lo + hi) >> 1;
      if (seg_ids[mid] < gtid) lo = mid + 1; else hi = mid;
    }
    seg_start[gtid] = lo;
  }
  __shared__ __align__(16) float s_lds[BB * PP];  // [b][p]
  for (int i = tid; i < BB * PP; i += 256) {
    int p = i >> 3, b = i & 7;
    s_lds[b * PP + p] = S[p * JJ + idx[b]];
  }
  __syncthreads();
  int n = blockIdx.x * 64 + (tid >> 2);
  int sub = tid & 3;
  const float4* Kp = reinterpret_cast<const float4*>(Kmat + (size_t)n * PP + sub * 16);
  float4 kq[4];
#pragma unroll
  for (int j = 0; j < 4; ++j) kq[j] = Kp[j];
  float acc[8];
#pragma unroll
  for (int b = 0; b < 8; ++b) acc[b] = 0.f;
#pragma unroll
  for (int j4 = 0; j4 < 4; ++j4) {
    float4 kk = kq[j4];
#pragma unroll
    for (int b = 0; b < 8; ++b) {
      const float4 sv = *reinterpret_cast<const float4*>(&s_lds[b * PP + sub * 16 + j4 * 4]);
      acc[b] += kk.x * sv.x + kk.y * sv.y + kk.z * sv.z + kk.w * sv.w;
    }
  }
#pragma unroll
  for (int b = 0; b < 8; ++b) {
    acc[b] += __shfl_xor(acc[b], 1);
    acc[b] += __shfl_xor(acc[b], 2);
  }
  float ox = (sub == 0) ? acc[0] : (sub == 1) ? acc[2] : (sub == 2) ? acc[4] : acc[6];
  float oy = (sub == 0) ? acc[1] : (sub == 1) ? acc[3] : (sub == 2) ? acc[5] : acc[7];
  reinterpret_cast<float2*>(ew + (size_t)n * 8)[sub] =
      make_float2(__expf(ox), __expf(oy));
}

// ------- kernel 2: SHUFFLE-FREE segment sums via scalar ew loads ------------
// Block = 1 segment, 4 slice-waves. Lane owns q = lane. Per row: one
// wave-uniform s_load_dwordx8 of ew[r][0..7] (SMEM pipe, SGPR operands),
// one coalesced 256B V row load, 8 FMA + 8 adds. NO shuffles, NO LDS in
// the loop. Single tiny LDS epilogue per wave.
__global__ __launch_bounds__(256) void k_segS(const float* __restrict__ ew,
                                              const float* __restrict__ V,
                                              const int* __restrict__ seg_start,
                                              float* __restrict__ M) {
  __shared__ __align__(16) float accred[4][8][64];
  __shared__ float reds[4][8];
  int tid = threadIdx.x;
  int t = blockIdx.x;
  int lane = tid & 63;
  int w = __builtin_amdgcn_readfirstlane(tid >> 6);   // wave-uniform slice id
  int s = seg_start[t], e = seg_start[t + 1];
  int len = e - s;
  int chunk = (len + 3) >> 2;
  int b0 = __builtin_amdgcn_readfirstlane(s + w * chunk);
  int b1 = b0 + chunk; if (b1 > e) b1 = e;
  b1 = __builtin_amdgcn_readfirstlane(b1);
  if (b1 < b0) b1 = b0;

  float acc[8], se[8];
#pragma unroll
  for (int b = 0; b < 8; ++b) { acc[b] = 0.f; se[b] = 0.f; }

  int r = b0;
  for (; r + 4 <= b1; r += 4) {
#pragma unroll
    for (int u = 0; u < 4; ++u) {
      const float* er = ew + (size_t)(r + u) * 8;   // wave-uniform -> s_load
      float e0 = er[0], e1 = er[1], e2 = er[2], e3 = er[3];
      float e4 = er[4], e5 = er[5], e6 = er[6], e7 = er[7];
      float v = V[(size_t)(r + u) * QQ + lane];
      acc[0] += e0 * v; acc[1] += e1 * v; acc[2] += e2 * v; acc[3] += e3 * v;
      acc[4] += e4 * v; acc[5] += e5 * v; acc[6] += e6 * v; acc[7] += e7 * v;
      se[0] += e0; se[1] += e1; se[2] += e2; se[3] += e3;
      se[4] += e4; se[5] += e5; se[6] += e6; se[7] += e7;
    }
  }
  for (; r < b1; ++r) {
    const float* er = ew + (size_t)r * 8;
    float e0 = er[0], e1 = er[1], e2 = er[2], e3 = er[3];
    float e4 = er[4], e5 = er[5], e6 = er[6], e7 = er[7];
    float v = V[(size_t)r * QQ + lane];
    acc[0] += e0 * v; acc[1] += e1 * v; acc[2] += e2 * v; acc[3] += e3 * v;
    acc[4] += e4 * v; acc[5] += e5 * v; acc[6] += e6 * v; acc[7] += e7 * v;
    se[0] += e0; se[1] += e1; se[2] += e2; se[3] += e3;
    se[4] += e4; se[5] += e5; se[6] += e6; se[7] += e7;
  }

  // ---- tiny epilogue: 8 LDS stores per lane + cross-wave combine ----
#pragma unroll
  for (int b = 0; b < 8; ++b) accred[w][b][lane] = acc[b];
  if (lane == 0) {
#pragma unroll
    for (int b = 0; b < 8; ++b) reds[w][b] = se[b];
  }
  __syncthreads();
  for (int o = tid; o < 512; o += 256) {
    int b = o >> 6, q = o & 63;
    float dd = reds[0][b] + reds[1][b] + reds[2][b] + reds[3][b];
    float inv = (dd > 0.f) ? 1.f / dd : 0.f;
    float sum = accred[0][b][q] + accred[1][b][q] + accred[2][b][q] + accred[3][b][q];
    M[(size_t)t * 512 + o] = sum * inv;   // M[t][b][q]
  }
}

// -------- kernel 3: GI[rho][g] = W_ih[g,:] . X[rho,:] + b_ih ----------------
__global__ __launch_bounds__(256) void k_gi(const float* __restrict__ M,
                                            const float* __restrict__ W_ih,
                                            const float* __restrict__ b_ih,
                                            float* __restrict__ GI) {
  __shared__ float Wt[64 * 193];
  int tid = threadIdx.x;
  for (int i = tid; i < 192 * 64; i += 256) {
    int g = i >> 6, k = i & 63;
    Wt[k * 193 + g] = W_ih[i];
  }
  __syncthreads();
  int lane = tid & 63, wv = tid >> 6;
  int row0 = blockIdx.x * 32 + wv * 8;
  float x[8];
#pragma unroll
  for (int rr = 0; rr < 8; ++rr) {
    int rho = row0 + rr;
    int b = rho >> 11, t = rho & 2047;
    x[rr] = M[((size_t)t * 8 + b) * 64 + lane];
  }
  float bi0 = b_ih[lane], bi1 = b_ih[64 + lane], bi2 = b_ih[128 + lane];
  float a0[8], a1[8], a2[8];
#pragma unroll
  for (int rr = 0; rr < 8; ++rr) { a0[rr] = bi0; a1[rr] = bi1; a2[rr] = bi2; }
#pragma unroll
  for (int k = 0; k < 64; ++k) {
    float w0 = Wt[k * 193 + lane];
    float w1 = Wt[k * 193 + 64 + lane];
    float w2 = Wt[k * 193 + 128 + lane];
#pragma unroll
    for (int rr = 0; rr < 8; ++rr) {
      float xk = lane_bcast(x[rr], k);
      a0[rr] += w0 * xk; a1[rr] += w1 * xk; a2[rr] += w2 * xk;
    }
  }
#pragma unroll
  for (int rr = 0; rr < 8; ++rr) {
    size_t rho = (size_t)row0 + rr;
    GI[rho * 192 + lane]       = a0[rr];
    GI[rho * 192 + 64 + lane]  = a1[rr];
    GI[rho * 192 + 128 + lane] = a2[rr];
  }
}

// -------- kernel 4: GRU, one t-row per wave, b128 W reads, padded LDS -------
__global__ __launch_bounds__(256) void k_gru(const float* __restrict__ GI,
                                             const float* __restrict__ W_hh,
                                             const float* __restrict__ b_hh,
                                             const float* __restrict__ w_out,
                                             const float* __restrict__ b_out,
                                             float* __restrict__ preds) {
  __shared__ __align__(16) float Wl[192 * 68];
  int tid = threadIdx.x;
  for (int i = tid; i < 192 * 16; i += 256) {
    int g = i >> 4, c = i & 15;
    *reinterpret_cast<float4*>(&Wl[g * 68 + c * 4]) =
        *reinterpret_cast<const float4*>(W_hh + g * 64 + c * 4);
  }
  __syncthreads();
  int lane = tid & 63, wv = tid >> 6;
  int t = blockIdx.x * 4 + wv;
  float bh0 = b_hh[lane], bh1 = b_hh[64 + lane], bh2 = b_hh[128 + lane];
  float wo = w_out[lane];
  float bo = b_out[0];
  const float* w0base = &Wl[lane * 68];
  const float* w1base = &Wl[(64 + lane) * 68];
  const float* w2base = &Wl[(128 + lane) * 68];

  float gr[8], gz[8], gn[8];
#pragma unroll
  for (int b = 0; b < 8; ++b) {
    size_t base = ((size_t)b * TT + t) * 192;
    gr[b] = GI[base + lane];
    gz[b] = GI[base + 64 + lane];
    gn[b] = GI[base + 128 + lane];
  }

  float h;
  {
    float r = 1.f / (1.f + __expf(-(gr[0] + bh0)));
    float z = 1.f / (1.f + __expf(-(gz[0] + bh1)));
    float nv = tanhf(gn[0] + r * bh2);
    h = (1.f - z) * nv;
    float pv = h * wo;
#pragma unroll
    for (int off = 32; off; off >>= 1) pv += __shfl_xor(pv, off);
    if (lane == 0) preds[t] = pv + bo;
  }
#pragma unroll
  for (int b = 1; b < 8; ++b) {
    float ar = bh0, az = bh1, an = bh2;
#pragma unroll
    for (int c = 0; c < 16; ++c) {
      const float4 w0 = *reinterpret_cast<const float4*>(w0base + c * 4);
      const float4 w1 = *reinterpret_cast<const float4*>(w1base + c * 4);
      const float4 w2 = *reinterpret_cast<const float4*>(w2base + c * 4);
      float a0 = lane_bcast(h, c * 4 + 0), a1 = lane_bcast(h, c * 4 + 1);
      float a2 = lane_bcast(h, c * 4 + 2), a3 = lane_bcast(h, c * 4 + 3);
      ar += w0.x * a0 + w0.y * a1 + w0.z * a2 + w0.w * a3;
      az += w1.x * a0 + w1.y * a1 + w1.z * a2 + w1.w * a3;
      an += w2.x * a0 + w2.y * a1 + w2.z * a2 + w2.w * a3;
    }
    float r = 1.f / (1.f + __expf(-(gr[b] + ar)));
    float z = 1.f / (1.f + __expf(-(gz[b] + az)));
    float nv = tanhf(gn[b] + r * an);
    h = (1.f - z) * nv + z * h;
    float pv = h * wo;
#pragma unroll
    for (int off = 32; off; off >>= 1) pv += __shfl_xor(pv, off);
    if (lane == 0) preds[(size_t)b * TT + t] = pv + bo;
  }
}

extern "C" void kernel_launch(void* const* d_in, const int* in_sizes, int n_in,
                              void* d_out, int out_size, void* d_ws, size_t ws_size,
                              hipStream_t stream) {
  const int*   idx     = (const int*)d_in[0];
  const int*   seg_ids = (const int*)d_in[1];
  const float* Kmat    = (const float*)d_in[2];
  const float* V       = (const float*)d_in[3];
  const float* S       = (const float*)d_in[4];
  const float* W_ih    = (const float*)d_in[5];
  const float* W_hh    = (const float*)d_in[6];
  const float* b_ih    = (const float*)d_in[7];
  const float* b_hh    = (const float*)d_in[8];
  const float* w_out   = (const float*)d_in[9];
  const float* b_out   = (const float*)d_in[10];
  float* out = (float*)d_out;

  char* ws = (char*)d_ws;
  int*   seg_start = (int*)(ws + 0);       // (T+1) ints         8448 B
  float* ew = (float*)(ws + 8448);         // N*8 f              8.4 MB
  float* M  = (float*)(ws + 8397056);      // T*8*64 f           4.2 MB
  float* GI = (float*)(ws + 12591360);     // 8*T*192 f         12.6 MB

  hipLaunchKernelGGL(k_wp, dim3(NN / 64), dim3(256), 0, stream,
                     Kmat, idx, S, seg_ids, ew, seg_start);
  hipLaunchKernelGGL(k_segS, dim3(TT), dim3(256), 0, stream, ew, V, seg_start, M);
  hipLaunchKernelGGL(k_gi, dim3(512), dim3(256), 0, stream, M, W_ih, b_ih, GI);
  hipLaunchKernelGGL(k_gru, dim3(512), dim3(256), 0, stream, GI, W_hh, b_hh, w_out, b_out, out);
}